// Round 16
// baseline (1191.522 us; speedup 1.0000x reference)
//
#include <hip/hip_runtime.h>

typedef _Float16 f16;
typedef f16 f16x2 __attribute__((ext_vector_type(2)));
typedef f16 f16x4 __attribute__((ext_vector_type(4)));
typedef f16 f16x8 __attribute__((ext_vector_type(8)));
typedef float f32x4 __attribute__((ext_vector_type(4)));
typedef const void __attribute__((address_space(1)))* gas1;
typedef void __attribute__((address_space(3)))* las3;

#define NB 4096
#define NN 21
#define MROWS (NB*NN)      // 86016
#define CIN 512

// ---------------- adjacency ----------------
__global__ void k_adj(const float* __restrict__ nv1, const float* __restrict__ nv2,
                      float* __restrict__ Aout) {
  __shared__ float at[21][21];
  __shared__ float dinv[21];
  int t = threadIdx.x;
  if (t < 441) {
    int i = t / 21, j = t % 21;
    float s = 0.f;
    #pragma unroll
    for (int r = 0; r < 10; r++) s += nv1[i*10 + r] * nv2[r*21 + j];
    float v = 1.f / (1.f + expf(-s));
    if (i == j) v += 1.f;
    at[i][j] = v;
  }
  __syncthreads();
  if (t < 21) {
    float d = 0.f;
    #pragma unroll
    for (int j = 0; j < 21; j++) d += at[t][j];
    dinv[t] = d > 0.f ? rsqrtf(d) : 0.f;
  }
  __syncthreads();
  if (t < 441) {
    int i = t / 21, j = t % 21;
    float a = dinv[i] * at[i][j] * dinv[j];
    Aout[t] = a > 0.1f ? a : 0.f;
  }
}

// ------- batched transpose: all 5 weight matrices in one launch -------
__global__ void k_transpose_all(const float* __restrict__ s0, const float* __restrict__ s1,
                                const float* __restrict__ s2, const float* __restrict__ s3,
                                const float* __restrict__ s4,
                                f16* __restrict__ d0, f16* __restrict__ d1,
                                f16* __restrict__ d2, f16* __restrict__ d3,
                                f16* __restrict__ d4) {
  __shared__ float tile[32][33];
  int b = blockIdx.x;
  const float* src; f16* dst; int K, N, local;
  if (b < 512)       { src = s0; dst = d0; K = 512;  N = 1024; local = b; }
  else if (b < 1024) { src = s1; dst = d1; K = 512;  N = 1024; local = b - 512; }
  else if (b < 2048) { src = s2; dst = d2; K = 1024; N = 1024; local = b - 1024; }
  else if (b < 2560) { src = s3; dst = d3; K = 1024; N = 512;  local = b - 2048; }
  else               { src = s4; dst = d4; K = 512;  N = 1024; local = b - 2560; }
  int ntn = N >> 5;
  int n0 = (local % ntn) * 32, k0 = (local / ntn) * 32;
  int tx = threadIdx.x, ty = threadIdx.y;
  #pragma unroll
  for (int i = 0; i < 4; i++)
    tile[ty + 8*i][tx] = src[(size_t)(k0 + ty + 8*i) * N + n0 + tx];
  __syncthreads();
  #pragma unroll
  for (int i = 0; i < 4; i++)
    dst[(size_t)(n0 + ty + 8*i) * K + k0 + tx] = (f16)tile[tx][ty + 8*i];
}

// ---------------- node mean over 21 (float2-vectorized, 1 pair/thread) ------
__global__ void k_mean(const float* __restrict__ x, float* __restrict__ xm) {
  int b = blockIdx.x, c0 = threadIdx.x * 2;
  const float* xb = x + (size_t)b * NN * 512 + c0;
  float s0 = 0.f, s1 = 0.f;
  #pragma unroll
  for (int n = 0; n < NN; n++) {
    float2 v = *(const float2*)(xb + (size_t)n * 512);
    s0 += v.x; s1 += v.y;
  }
  float2 o; o.x = s0 * (1.f/21.f); o.y = s1 * (1.f/21.f);
  *(float2*)(xm + (size_t)b * 512 + c0) = o;
}

// ---------------- SE matmuls ----------------
__global__ void k_se1(const float* __restrict__ xm, const float* __restrict__ w1,
                      float* __restrict__ y1) {
  __shared__ float row[CIN];
  int b = blockIdx.x, t = threadIdx.x;   // 128 threads
  for (int k = t; k < CIN; k += 128) row[k] = xm[(size_t)b*CIN + k];
  __syncthreads();
  float acc = 0.f;
  for (int k = 0; k < CIN; k++) acc += row[k] * w1[(size_t)k*128 + t];
  y1[(size_t)b*128 + t] = fmaxf(acc, 0.f);
}

__global__ void k_se2(const float* __restrict__ y1, const float* __restrict__ w2,
                      float* __restrict__ y) {
  __shared__ float row[128];
  int b = blockIdx.x, t = threadIdx.x;   // 512 threads
  if (t < 128) row[t] = y1[(size_t)b*128 + t];
  __syncthreads();
  float acc = 0.f;
  for (int k = 0; k < 128; k++) acc += row[k] * w2[(size_t)k*CIN + t];
  y[(size_t)b*CIN + t] = 1.f / (1.f + expf(-acc));
}

// ---------------- gating: xg = f16(x * y[graph]) ----------------
__global__ void k_gate(const float* __restrict__ x, const float* __restrict__ y,
                       f16* __restrict__ xg) {
  size_t i8 = (size_t)blockIdx.x * 256 + threadIdx.x;
  size_t base = i8 * 8;
  int r = (int)(base >> 9);          // /512
  int c = (int)(base & 511);
  int b = r / 21;
  const float4* xp = (const float4*)(x + base);
  const float4* yp = (const float4*)(y + (size_t)b*CIN + c);
  float4 a0 = xp[0], a1 = xp[1];
  float4 g0 = yp[0], g1 = yp[1];
  f16x8 o;
  o[0] = (f16)(a0.x * g0.x); o[1] = (f16)(a0.y * g0.y);
  o[2] = (f16)(a0.z * g0.z); o[3] = (f16)(a0.w * g0.w);
  o[4] = (f16)(a1.x * g1.x); o[5] = (f16)(a1.y * g1.y);
  o[6] = (f16)(a1.z * g1.z); o[7] = (f16)(a1.w * g1.w);
  *(f16x8*)(xg + base) = o;
}

// ======== 256x256 8-wave GEMM (r10 schedule + front-loaded staging) ========
// BK=64, dbuf 2x64KB LDS, 8 waves (2Mx4N), per-wave 128x64 out (acc[8][4]).
// r15 delta: ALL 8 staging issues of tile t+1 are front-loaded before MFMA
// cluster 1 (r10 issued the last 4 between clusters -> only ~600cy cover for
// ~900cy HBM latency -> ~300-500cy exposed per tile at the vmcnt(0) drain).
// Front-loading gives the last issues ~2 clusters (~1200cy) of compute cover.
// Race-freedom identical to r10: staging writes buf[(t+1)&1], reads are from
// buf[t&1]. vmcnt(0)+1 barrier per K-tile. MFMA operands swapped (mfma(bv,av))
// -> 4 consecutive C-cols per acc reg -> vectorized f16x4/float4 stores.
// T2 granule-XOR swizzle on global source + ds_read (LDS dest linear).
// MODE 0: f16 out. MODE 1: f16 out + fused BN column-stat partials per m-block.
// MODE 2: f32 out + bias.
#define QBUF 65536

template<int MODE>
__global__ __launch_bounds__(512, 1)
void k_gemm256(const f16* __restrict__ A, const f16* __restrict__ BT,
               f16* __restrict__ C1, const float* __restrict__ bias,
               float* __restrict__ Cf, float* __restrict__ psum,
               float* __restrict__ psq, int N, int K, int lgn) {
  __shared__ __align__(16) char lds[2 * QBUF];
  const int tid = threadIdx.x;
  const int nwg = gridDim.x;
  const int g = blockIdx.x;
  const int swz = (g & 7) * (nwg >> 3) + (g >> 3);   // XCD-chunked, nwg%8==0
  const int bn = swz & ((1 << lgn) - 1);             // N fastest: A-panel L2 reuse
  const int bm = swz >> lgn;
  const int lane = tid & 63;
  const int wid = tid >> 6;
  const int wr = wid >> 2;          // 0..1 : 128-row half
  const int wc = wid & 3;           // 0..3 : 64-col slab
  const int fr = lane & 15;
  const int kg = lane >> 4;         // 0..3

  // staging: 8 granule-sets/thread/K-tile; gid=j*512+tid; j<4 -> A, else B.
  // LDS dest = gid*16 (linear); source granule pre-swizzled gr^(row&7).
  int srcOff[8];
  #pragma unroll
  for (int j = 0; j < 8; j++) {
    int gid = j * 512 + tid;
    int row = (gid >> 3) & 255;
    int gr = gid & 7;
    int gsw = gr ^ (row & 7);
    srcOff[j] = ((j < 4 ? bm : bn) * 256 + row) * K + gsw * 8;
  }
  const int ldsBase = tid * 16;     // + j*8192

  const int x7 = fr & 7;                       // swizzle key (row&7 == fr&7)
  const int aBase = (wr*128 + fr) * 128;       // + m*2048
  const int bBase = 32768 + (wc*64 + fr) * 128;// + n*2048

  f32x4 acc[8][4];
  #pragma unroll
  for (int m = 0; m < 8; m++)
    #pragma unroll
    for (int n = 0; n < 4; n++)
      #pragma unroll
      for (int r = 0; r < 4; r++) acc[m][n][r] = 0.f;

  auto STAGEH = [&](int t2, int sbuf, int j0) {   // 2 wave-loads = 16 KB
    char* dst = (char*)lds + sbuf * QBUF;
    const size_t kof = (size_t)t2 * 64;
    #pragma unroll
    for (int j = j0; j < j0 + 2; j++) {
      const f16* src = (j < 4 ? A : BT) + srcOff[j] + kof;
      __builtin_amdgcn_global_load_lds((gas1)src, (las3)(dst + ldsBase + j*8192), 16, 0, 0);
    }
  };
  auto READF = [&](f16x8* av, f16x8* bv, const char* rb, int s) {
    const int ko = ((s*4 + kg) ^ x7) << 4;
    #pragma unroll
    for (int m = 0; m < 8; m++) av[m] = *(const f16x8*)(rb + aBase + m*2048 + ko);
    #pragma unroll
    for (int n = 0; n < 4; n++) bv[n] = *(const f16x8*)(rb + bBase + n*2048 + ko);
  };

  f16x8 av[8], bv[4];
  const int NT = K >> 6;
  STAGEH(0, 0, 0); STAGEH(0, 0, 2); STAGEH(0, 0, 4); STAGEH(0, 0, 6);
  asm volatile("s_waitcnt vmcnt(0)" ::: "memory");
  asm volatile("s_barrier" ::: "memory");

  for (int t = 0; t < NT; t++) {
    const char* rb = (const char*)lds + (t & 1) * QBUF;
    const int nb = (t + 1) & 1;
    const bool stg = (t + 1) < NT;

    // front-load ALL of tile t+1's staging before cluster 1
    if (stg) {
      STAGEH(t + 1, nb, 0); STAGEH(t + 1, nb, 2);
      STAGEH(t + 1, nb, 4); STAGEH(t + 1, nb, 6);
    }
    READF(av, bv, rb, 0);
    __builtin_amdgcn_s_setprio(1);
    #pragma unroll
    for (int m = 0; m < 8; m++)
      #pragma unroll
      for (int n = 0; n < 4; n++)
        acc[m][n] = __builtin_amdgcn_mfma_f32_16x16x32_f16(bv[n], av[m], acc[m][n], 0, 0, 0);
    __builtin_amdgcn_s_setprio(0);
    READF(av, bv, rb, 1);
    __builtin_amdgcn_s_setprio(1);
    #pragma unroll
    for (int m = 0; m < 8; m++)
      #pragma unroll
      for (int n = 0; n < 4; n++)
        acc[m][n] = __builtin_amdgcn_mfma_f32_16x16x32_f16(bv[n], av[m], acc[m][n], 0, 0, 0);
    __builtin_amdgcn_s_setprio(0);
    if (stg) asm volatile("s_waitcnt vmcnt(0)" ::: "memory");
    asm volatile("s_barrier" ::: "memory");   // tile t+1 resident; buf[t&1] reads retired
  }

  // swapped-operand C layout: C[bm*256 + wr*128 + m*16 + fr]
  //                            [bn*256 + wc*64 + n*16 + kg*4 + r]
  const int crow = bm*256 + wr*128 + fr;    // + m*16
  const int ccol = bn*256 + wc*64 + kg*4;   // + n*16, r contiguous
  if constexpr (MODE == 2) {
    #pragma unroll
    for (int n = 0; n < 4; n++) {
      float4 bb = *(const float4*)(bias + ccol + n*16);
      #pragma unroll
      for (int m = 0; m < 8; m++) {
        float4 v;
        v.x = acc[m][n][0] + bb.x; v.y = acc[m][n][1] + bb.y;
        v.z = acc[m][n][2] + bb.z; v.w = acc[m][n][3] + bb.w;
        *(float4*)(Cf + (size_t)(crow + m*16) * N + ccol + n*16) = v;
      }
    }
  } else {
    #pragma unroll
    for (int m = 0; m < 8; m++)
      #pragma unroll
      for (int n = 0; n < 4; n++) {
        f16x4 o;
        o[0] = (f16)acc[m][n][0]; o[1] = (f16)acc[m][n][1];
        o[2] = (f16)acc[m][n][2]; o[3] = (f16)acc[m][n][3];
        *(f16x4*)(C1 + (size_t)(crow + m*16) * N + ccol + n*16) = o;
      }
  }
  if constexpr (MODE == 1) {
    // column-stat partials over this block's 256 rows.
    float s[4][4], q[4][4];
    #pragma unroll
    for (int n = 0; n < 4; n++)
      #pragma unroll
      for (int r = 0; r < 4; r++) {
        float ss = 0.f, qq = 0.f;
        #pragma unroll
        for (int m = 0; m < 8; m++) { float v = acc[m][n][r]; ss += v; qq = fmaf(v, v, qq); }
        s[n][r] = ss; q[n][r] = qq;
      }
    #pragma unroll
    for (int n = 0; n < 4; n++)
      #pragma unroll
      for (int r = 0; r < 4; r++) {
        s[n][r] += __shfl_xor(s[n][r], 1); s[n][r] += __shfl_xor(s[n][r], 2);
        s[n][r] += __shfl_xor(s[n][r], 4); s[n][r] += __shfl_xor(s[n][r], 8);
        q[n][r] += __shfl_xor(q[n][r], 1); q[n][r] += __shfl_xor(q[n][r], 2);
        q[n][r] += __shfl_xor(q[n][r], 4); q[n][r] += __shfl_xor(q[n][r], 8);
      }
    float* wred = (float*)lds;   // [sum: [wr][256]] [sq: [wr][256]] = 4 KB
    __syncthreads();
    if (fr == 0) {
      #pragma unroll
      for (int n = 0; n < 4; n++)
        #pragma unroll
        for (int r = 0; r < 4; r++) {
          int c = wc*64 + n*16 + kg*4 + r;
          wred[wr*256 + c]       = s[n][r];
          wred[512 + wr*256 + c] = q[n][r];
        }
    }
    __syncthreads();
    if (tid < 256) {
      psum[(size_t)bm * N + bn*256 + tid] = wred[tid]       + wred[256 + tid];
      psq [(size_t)bm * N + bn*256 + tid] = wred[512 + tid] + wred[768 + tid];
    }
  }
}

// ---------------- in-place mix on [M][512] (xg -> mix(xg)) ----------------
__global__ __launch_bounds__(256)
void k_mixip(f16* __restrict__ t, const float* __restrict__ Aadj) {
  __shared__ float A[441];
  int b = blockIdx.x, tid = threadIdx.x;
  for (int i = tid; i < 441; i += 256) A[i] = Aadj[i];
  __syncthreads();
  int c0 = tid * 2;
  size_t base = (size_t)b * NN * 512 + c0;
  float vx[21], vy[21];
  #pragma unroll
  for (int j = 0; j < 21; j++) {
    f16x2 v = *(const f16x2*)(t + base + (size_t)j * 512);
    vx[j] = (float)v[0]; vy[j] = (float)v[1];
  }
  #pragma unroll
  for (int i = 0; i < 21; i++) {
    float a0 = 0.f, a1 = 0.f;
    #pragma unroll
    for (int j = 0; j < 21; j++) { float w = A[i*21+j]; a0 = fmaf(w, vx[j], a0); a1 = fmaf(w, vy[j], a1); }
    f16x2 o; o[0] = (f16)a0; o[1] = (f16)a1;
    *(f16x2*)(t + base + (size_t)i * 512) = o;
  }
}

// ------- per-graph 21x21 mix, in-place + per-graph BN stats -------
__global__ __launch_bounds__(256)
void k_mix(f16* __restrict__ t, const float* __restrict__ Aadj,
           float* __restrict__ psum, float* __restrict__ psq, int C) {
  __shared__ float A[441];
  int b = blockIdx.x, tid = threadIdx.x;
  for (int i = tid; i < 441; i += 256) A[i] = Aadj[i];
  __syncthreads();
  int c0 = (blockIdx.y * 256 + tid) * 2;
  size_t base = (size_t)b * NN * C + c0;
  float vx[21], vy[21];
  #pragma unroll
  for (int j = 0; j < 21; j++) {
    f16x2 v = *(const f16x2*)(t + base + (size_t)j * C);
    vx[j] = (float)v[0]; vy[j] = (float)v[1];
  }
  float s0 = 0.f, s1 = 0.f, q0 = 0.f, q1 = 0.f;
  #pragma unroll
  for (int i = 0; i < 21; i++) {
    float a0 = 0.f, a1 = 0.f;
    #pragma unroll
    for (int j = 0; j < 21; j++) {
      float w = A[i*21 + j];
      a0 = fmaf(w, vx[j], a0);
      a1 = fmaf(w, vy[j], a1);
    }
    f16x2 o; o[0] = (f16)a0; o[1] = (f16)a1;
    *(f16x2*)(t + base + (size_t)i * C) = o;
    s0 += a0; s1 += a1;
    q0 = fmaf(a0, a0, q0); q1 = fmaf(a1, a1, q1);
  }
  float2 sv; sv.x = s0; sv.y = s1;
  float2 qv; qv.x = q0; qv.y = q1;
  *(float2*)(psum + (size_t)b * C + c0) = sv;
  *(float2*)(psq  + (size_t)b * C + c0) = qv;
}

// ---------------- reduce partials -> groups (deterministic) --------------
__global__ void k_reduce(const float* __restrict__ ps, const float* __restrict__ pq,
                         float* __restrict__ rs, float* __restrict__ rq,
                         int C, int per) {
  int c = blockIdx.x * 256 + threadIdx.x;
  int py = blockIdx.y;
  float s = 0.f, q = 0.f;
  for (int p = py*per; p < py*per + per; p++) {
    s += ps[(size_t)p*C + c];
    q += pq[(size_t)p*C + c];
  }
  rs[(size_t)py*C + c] = s;
  rq[(size_t)py*C + c] = q;
}

__global__ void k_bnparams(const float* __restrict__ psum, const float* __restrict__ psq,
                           const float* __restrict__ gamma, const float* __restrict__ beta,
                           const float* __restrict__ resbias,
                           float* __restrict__ scale, float* __restrict__ shift,
                           int C, int npart) {
  int c = blockIdx.x * 256 + threadIdx.x;
  float s = 0.f, q = 0.f;
  for (int p = 0; p < npart; p++) { s += psum[(size_t)p*C + c]; q += psq[(size_t)p*C + c]; }
  const float Minv = 1.f / (float)MROWS;
  float mean = s * Minv;
  float var = q * Minv - mean * mean;
  float sc = gamma[c] * rsqrtf(var + 1e-5f);
  float sh = beta[c] - mean * sc;
  if (resbias) sh += resbias[c];
  scale[c] = sc; shift[c] = sh;
}

// ---------------- finalize: dst = relu(g*scale + shift + res) ----------------
__global__ void k_finalize(const f16* __restrict__ g, const f16* res,
                           f16* dst, const float* __restrict__ scale,
                           const float* __restrict__ shift, int cmask) {
  size_t i8 = (size_t)blockIdx.x * 256 + threadIdx.x;
  size_t base = i8 * 8;
  int c = (int)(base & (size_t)cmask);
  f16x8 gv = *(const f16x8*)(g + base);
  f16x8 rv = *(const f16x8*)(res + base);
  f16x8 o;
  #pragma unroll
  for (int j = 0; j < 8; j++) {
    float v = (float)gv[j] * scale[c + j] + shift[c + j] + (float)rv[j];
    o[j] = (f16)fmaxf(v, 0.f);
  }
  *(f16x8*)(dst + base) = o;
}

// ---------------- fused finish + mix: hmix = mix(relu(t*sc+sh+res)) ---------
__global__ __launch_bounds__(256)
void k_finmix(const f16* t, const f16* res, f16* hout, f16* hmix,
              const float* __restrict__ scale, const float* __restrict__ shift,
              const float* __restrict__ Aadj, int C) {
  __shared__ float A[441];
  int b = blockIdx.x, tid = threadIdx.x;
  for (int i = tid; i < 441; i += 256) A[i] = Aadj[i];
  __syncthreads();
  int c0 = (blockIdx.y * 256 + tid) * 2;
  float scx = scale[c0], scy = scale[c0+1];
  float shx = shift[c0], shy = shift[c0+1];
  size_t base = (size_t)b * NN * C + c0;
  float hx[21], hy[21];
  #pragma unroll
  for (int j = 0; j < 21; j++) {
    f16x2 tv = *(const f16x2*)(t + base + (size_t)j*C);
    f16x2 rv = *(const f16x2*)(res + base + (size_t)j*C);
    hx[j] = fmaxf((float)tv[0]*scx + shx + (float)rv[0], 0.f);
    hy[j] = fmaxf((float)tv[1]*scy + shy + (float)rv[1], 0.f);
    if (hout) {
      f16x2 o; o[0] = (f16)hx[j]; o[1] = (f16)hy[j];
      *(f16x2*)(hout + base + (size_t)j*C) = o;
    }
  }
  #pragma unroll
  for (int i = 0; i < 21; i++) {
    float a0 = 0.f, a1 = 0.f;
    #pragma unroll
    for (int j = 0; j < 21; j++) { float w = A[i*21+j]; a0 = fmaf(w, hx[j], a0); a1 = fmaf(w, hy[j], a1); }
    f16x2 o; o[0] = (f16)a0; o[1] = (f16)a1;
    *(f16x2*)(hmix + base + (size_t)i*C) = o;
  }
}

// ---------------- pool (mean over 21) + BN affine -> f16 (f16x2 vec) --------
__global__ void k_pool(const f16* __restrict__ g3, const float* __restrict__ scale,
                       const float* __restrict__ shift, f16* __restrict__ pooled) {
  int b = blockIdx.x, c0 = threadIdx.x * 2;
  const f16* gb = g3 + (size_t)b * NN * 512 + c0;
  float s0 = 0.f, s1 = 0.f;
  #pragma unroll
  for (int n = 0; n < NN; n++) {
    f16x2 v = *(const f16x2*)(gb + (size_t)n * 512);
    s0 += (float)v[0]; s1 += (float)v[1];
  }
  f16x2 o;
  o[0] = (f16)((s0 * (1.f/21.f)) * scale[c0]   + shift[c0]);
  o[1] = (f16)((s1 * (1.f/21.f)) * scale[c0+1] + shift[c0+1]);
  *(f16x2*)(pooled + (size_t)b * 512 + c0) = o;
}

extern "C" void kernel_launch(void* const* d_in, const int* in_sizes, int n_in,
                              void* d_out, int out_size, void* d_ws, size_t ws_size,
                              hipStream_t stream) {
  const float* x     = (const float*)d_in[0];
  const float* nv1   = (const float*)d_in[2];
  const float* nv2   = (const float*)d_in[3];
  const float* se_w1 = (const float*)d_in[4];
  const float* se_w2 = (const float*)d_in[5];
  const float* W1    = (const float*)d_in[6];
  const float* W2    = (const float*)d_in[8];
  const float* W3    = (const float*)d_in[10];
  const float* bn1g  = (const float*)d_in[12];
  const float* bn1b  = (const float*)d_in[13];
  const float* bn2g  = (const float*)d_in[14];
  const float* bn2b  = (const float*)d_in[15];
  const float* bn3g  = (const float*)d_in[16];
  const float* bn3b  = (const float*)d_in[17];
  const float* rs1w  = (const float*)d_in[18];
  const float* rs1b  = (const float*)d_in[19];
  const float* fcw   = (const float*)d_in[20];
  const float* fcb   = (const float*)d_in[21];
  float* out = (float*)d_out;

  char* ws = (char*)d_ws;
  size_t off = 0;
  auto alloc = [&](size_t bytes) -> char* {
    char* p = ws + off;
    off = (off + bytes + 255) & ~(size_t)255;
    return p;
  };

  // total ws footprint ~470 MB (known-good <=484; 738 aborted in round 7)
  float* A_adj = (float*)alloc(441 * 4);
  f16* W1T  = (f16*)alloc((size_t)1024 * 512 * 2);
  f16* RS1T = (f16*)alloc((size_t)1024 * 512 * 2);
  f16* W2T  = (f16*)alloc((size_t)1024 * 1024 * 2);
  f16* W3T  = (f16*)alloc((size_t)512 * 1024 * 2);
  f16* FCWT = (f16*)alloc((size_t)1024 * 512 * 2);
  float* psum = (float*)alloc((size_t)NB * 1024 * 4);    // 16MB; aliases xm
  float* psq  = (float*)alloc((size_t)NB * 1024 * 4);    // 16MB; aliases yv
  float* y1   = (float*)alloc((size_t)NB * 128 * 4);
  float* rsum = (float*)alloc((size_t)32 * 1024 * 4);
  float* rsq  = (float*)alloc((size_t)32 * 1024 * 4);
  float* sc1 = (float*)alloc(1024 * 4);
  float* sh1 = (float*)alloc(1024 * 4);
  float* sc2 = (float*)alloc(1024 * 4);
  float* sh2 = (float*)alloc(1024 * 4);
  float* sc3 = (float*)alloc(1024 * 4);
  float* sh3 = (float*)alloc(1024 * 4);
  f16* pooled = (f16*)alloc((size_t)NB * 512 * 2);
  f16* G = (f16*)alloc((size_t)MROWS * 512 * 2);     // xg -> xgm -> T3
  f16* R = (f16*)alloc((size_t)MROWS * 1024 * 2);    // R1 -> h1
  f16* T = (f16*)alloc((size_t)MROWS * 1024 * 2);    // T1 -> T2/t2m -> h2m
  float* xm = psum;   // dead before psum first written
  float* yv = psq;    // dead after k_gate, before psq first written
  (void)ws_size; (void)in_sizes; (void)n_in; (void)out_size;

  // adjacency + batched weight transposes (1 launch)
  k_adj<<<1, 512, 0, stream>>>(nv1, nv2, A_adj);
  k_transpose_all<<<3072, dim3(32, 8), 0, stream>>>(W1, rs1w, W2, W3, fcw,
                                                    W1T, RS1T, W2T, W3T, FCWT);

  // SE path + gate
  k_mean<<<NB, 256, 0, stream>>>(x, xm);
  k_se1<<<NB, 128, 0, stream>>>(xm, se_w1, y1);
  k_se2<<<NB, 512, 0, stream>>>(y1, se_w2, yv);
  k_gate<<<21504, 256, 0, stream>>>(x, yv, G);

  // layer 1: R1 = xg@rs1w; xgm = mix(xg) in place; T1 = xgm@W1 (+fused stats)
  // M-tiles = 86016/256 = 336; N=1024 -> 4 N-tiles (lgn=2) -> 1344 blocks
  k_gemm256<0><<<1344, 512, 0, stream>>>(G, RS1T, R, nullptr, nullptr, nullptr, nullptr, 1024, 512, 2);
  k_mixip<<<NB, 256, 0, stream>>>(G, A_adj);
  k_gemm256<1><<<1344, 512, 0, stream>>>(G, W1T, T, nullptr, nullptr, psum, psq, 1024, 512, 2);
  k_reduce<<<dim3(4, 24), 256, 0, stream>>>(psum, psq, rsum, rsq, 1024, 14);   // 24*14 = 336
  k_bnparams<<<4, 256, 0, stream>>>(rsum, rsq, bn1g, bn1b, rs1b, sc1, sh1, 1024, 24);
  k_finalize<<<43008, 256, 0, stream>>>(T, R, R, sc1, sh1, 1023);     // h1 -> R

  // layer 2: T2 = h1@W2; mix+stats in place; h2m = mix(relu(BN(t2m)+h1)) -> T
  k_gemm256<0><<<1344, 512, 0, stream>>>(R, W2T, T, nullptr, nullptr, nullptr, nullptr, 1024, 1024, 2);
  k_mix<<<dim3(NB, 2), 256, 0, stream>>>(T, A_adj, psum, psq, 1024);
  k_reduce<<<dim3(4, 32), 256, 0, stream>>>(psum, psq, rsum, rsq, 1024, 128);
  k_bnparams<<<4, 256, 0, stream>>>(rsum, rsq, bn2g, bn2b, nullptr, sc2, sh2, 1024, 32);
  k_finmix<<<dim3(NB, 2), 256, 0, stream>>>(T, R, nullptr, T, sc2, sh2, A_adj, 1024);

  // layer 3: T3 = h2m@W3 (+fused stats) -> G ; N=512 -> 2 N-tiles (lgn=1)
  k_gemm256<1><<<672, 512, 0, stream>>>(T, W3T, G, nullptr, nullptr, psum, psq, 512, 1024, 1);
  k_reduce<<<dim3(2, 24), 256, 0, stream>>>(psum, psq, rsum, rsq, 512, 14);
  k_bnparams<<<2, 256, 0, stream>>>(rsum, rsq, bn3g, bn3b, nullptr, sc3, sh3, 512, 24);

  // pool + fc : M=4096 -> 16 m-tiles x 4 n-tiles = 64 blocks
  k_pool<<<NB, 256, 0, stream>>>(G, sc3, sh3, pooled);
  k_gemm256<2><<<64, 512, 0, stream>>>(pooled, FCWT, nullptr, fcb, out, nullptr, nullptr, 1024, 512, 2);
}

// Round 17
// 1164.992 us; speedup vs baseline: 1.0228x; 1.0228x over previous
//
#include <hip/hip_runtime.h>

typedef _Float16 f16;
typedef f16 f16x2 __attribute__((ext_vector_type(2)));
typedef f16 f16x4 __attribute__((ext_vector_type(4)));
typedef f16 f16x8 __attribute__((ext_vector_type(8)));
typedef float f32x4 __attribute__((ext_vector_type(4)));
typedef const void __attribute__((address_space(1)))* gas1;
typedef void __attribute__((address_space(3)))* las3;

#define NB 4096
#define NN 21
#define MROWS (NB*NN)      // 86016
#define CIN 512

// ---------------- adjacency ----------------
__global__ void k_adj(const float* __restrict__ nv1, const float* __restrict__ nv2,
                      float* __restrict__ Aout) {
  __shared__ float at[21][21];
  __shared__ float dinv[21];
  int t = threadIdx.x;
  if (t < 441) {
    int i = t / 21, j = t % 21;
    float s = 0.f;
    #pragma unroll
    for (int r = 0; r < 10; r++) s += nv1[i*10 + r] * nv2[r*21 + j];
    float v = 1.f / (1.f + expf(-s));
    if (i == j) v += 1.f;
    at[i][j] = v;
  }
  __syncthreads();
  if (t < 21) {
    float d = 0.f;
    #pragma unroll
    for (int j = 0; j < 21; j++) d += at[t][j];
    dinv[t] = d > 0.f ? rsqrtf(d) : 0.f;
  }
  __syncthreads();
  if (t < 441) {
    int i = t / 21, j = t % 21;
    float a = dinv[i] * at[i][j] * dinv[j];
    Aout[t] = a > 0.1f ? a : 0.f;
  }
}

// ------- batched transpose: all 5 weight matrices in one launch -------
__global__ void k_transpose_all(const float* __restrict__ s0, const float* __restrict__ s1,
                                const float* __restrict__ s2, const float* __restrict__ s3,
                                const float* __restrict__ s4,
                                f16* __restrict__ d0, f16* __restrict__ d1,
                                f16* __restrict__ d2, f16* __restrict__ d3,
                                f16* __restrict__ d4) {
  __shared__ float tile[32][33];
  int b = blockIdx.x;
  const float* src; f16* dst; int K, N, local;
  if (b < 512)       { src = s0; dst = d0; K = 512;  N = 1024; local = b; }
  else if (b < 1024) { src = s1; dst = d1; K = 512;  N = 1024; local = b - 512; }
  else if (b < 2048) { src = s2; dst = d2; K = 1024; N = 1024; local = b - 1024; }
  else if (b < 2560) { src = s3; dst = d3; K = 1024; N = 512;  local = b - 2048; }
  else               { src = s4; dst = d4; K = 512;  N = 1024; local = b - 2560; }
  int ntn = N >> 5;
  int n0 = (local % ntn) * 32, k0 = (local / ntn) * 32;
  int tx = threadIdx.x, ty = threadIdx.y;
  #pragma unroll
  for (int i = 0; i < 4; i++)
    tile[ty + 8*i][tx] = src[(size_t)(k0 + ty + 8*i) * N + n0 + tx];
  __syncthreads();
  #pragma unroll
  for (int i = 0; i < 4; i++)
    dst[(size_t)(n0 + ty + 8*i) * K + k0 + tx] = (f16)tile[tx][ty + 8*i];
}

// ---------------- node mean over 21 (float2-vectorized, 1 pair/thread) ------
__global__ void k_mean(const float* __restrict__ x, float* __restrict__ xm) {
  int b = blockIdx.x, c0 = threadIdx.x * 2;
  const float* xb = x + (size_t)b * NN * 512 + c0;
  float s0 = 0.f, s1 = 0.f;
  #pragma unroll
  for (int n = 0; n < NN; n++) {
    float2 v = *(const float2*)(xb + (size_t)n * 512);
    s0 += v.x; s1 += v.y;
  }
  float2 o; o.x = s0 * (1.f/21.f); o.y = s1 * (1.f/21.f);
  *(float2*)(xm + (size_t)b * 512 + c0) = o;
}

// ---------------- SE matmuls ----------------
__global__ void k_se1(const float* __restrict__ xm, const float* __restrict__ w1,
                      float* __restrict__ y1) {
  __shared__ float row[CIN];
  int b = blockIdx.x, t = threadIdx.x;   // 128 threads
  for (int k = t; k < CIN; k += 128) row[k] = xm[(size_t)b*CIN + k];
  __syncthreads();
  float acc = 0.f;
  for (int k = 0; k < CIN; k++) acc += row[k] * w1[(size_t)k*128 + t];
  y1[(size_t)b*128 + t] = fmaxf(acc, 0.f);
}

__global__ void k_se2(const float* __restrict__ y1, const float* __restrict__ w2,
                      float* __restrict__ y) {
  __shared__ float row[128];
  int b = blockIdx.x, t = threadIdx.x;   // 512 threads
  if (t < 128) row[t] = y1[(size_t)b*128 + t];
  __syncthreads();
  float acc = 0.f;
  for (int k = 0; k < 128; k++) acc += row[k] * w2[(size_t)k*CIN + t];
  y[(size_t)b*CIN + t] = 1.f / (1.f + expf(-acc));
}

// ---------------- gating: xg = f16(x * y[graph]) ----------------
__global__ void k_gate(const float* __restrict__ x, const float* __restrict__ y,
                       f16* __restrict__ xg) {
  size_t i8 = (size_t)blockIdx.x * 256 + threadIdx.x;
  size_t base = i8 * 8;
  int r = (int)(base >> 9);          // /512
  int c = (int)(base & 511);
  int b = r / 21;
  const float4* xp = (const float4*)(x + base);
  const float4* yp = (const float4*)(y + (size_t)b*CIN + c);
  float4 a0 = xp[0], a1 = xp[1];
  float4 g0 = yp[0], g1 = yp[1];
  f16x8 o;
  o[0] = (f16)(a0.x * g0.x); o[1] = (f16)(a0.y * g0.y);
  o[2] = (f16)(a0.z * g0.z); o[3] = (f16)(a0.w * g0.w);
  o[4] = (f16)(a1.x * g1.x); o[5] = (f16)(a1.y * g1.y);
  o[6] = (f16)(a1.z * g1.z); o[7] = (f16)(a1.w * g1.w);
  *(f16x8*)(xg + base) = o;
}

// ======== 256x256 8-wave GEMM (r10/r15 schedule — best measured) ========
// BK=64, dbuf 2x64KB LDS, 8 waves (2Mx4N), per-wave 128x64 out (acc[8][4]).
// Staging split into 4 half-stages: A-tile (4 loads) before cluster 1,
// B-tile (4 loads) between clusters; vmcnt(0)+1 barrier per K-tile.
// Schedule search CLOSED (6 variants): r11 counted/serial -20%, r12 4-phase
// interleave =, r14 slice-major counted -5% (+conflicts), r16 front-loaded
// -8% (VMEM issue congestion before cluster 1). This split is the optimum.
// MFMA operands swapped (mfma(bv,av)) -> 4 consecutive C-cols per acc reg ->
// vectorized f16x4/float4 stores. T2 granule-XOR swizzle (src + ds_read).
// MODE 0: f16 out. MODE 1: f16 out + fused BN column-stat partials per m-block.
// MODE 2: f32 out + bias.
#define QBUF 65536

template<int MODE>
__global__ __launch_bounds__(512, 1)
void k_gemm256(const f16* __restrict__ A, const f16* __restrict__ BT,
               f16* __restrict__ C1, const float* __restrict__ bias,
               float* __restrict__ Cf, float* __restrict__ psum,
               float* __restrict__ psq, int N, int K, int lgn) {
  __shared__ __align__(16) char lds[2 * QBUF];
  const int tid = threadIdx.x;
  const int nwg = gridDim.x;
  const int g = blockIdx.x;
  const int swz = (g & 7) * (nwg >> 3) + (g >> 3);   // XCD-chunked, nwg%8==0
  const int bn = swz & ((1 << lgn) - 1);             // N fastest: A-panel L2 reuse
  const int bm = swz >> lgn;
  const int lane = tid & 63;
  const int wid = tid >> 6;
  const int wr = wid >> 2;          // 0..1 : 128-row half
  const int wc = wid & 3;           // 0..3 : 64-col slab
  const int fr = lane & 15;
  const int kg = lane >> 4;         // 0..3

  // staging: 8 granule-sets/thread/K-tile; gid=j*512+tid; j<4 -> A, else B.
  // LDS dest = gid*16 (linear); source granule pre-swizzled gr^(row&7).
  int srcOff[8];
  #pragma unroll
  for (int j = 0; j < 8; j++) {
    int gid = j * 512 + tid;
    int row = (gid >> 3) & 255;
    int gr = gid & 7;
    int gsw = gr ^ (row & 7);
    srcOff[j] = ((j < 4 ? bm : bn) * 256 + row) * K + gsw * 8;
  }
  const int ldsBase = tid * 16;     // + j*8192

  const int x7 = fr & 7;                       // swizzle key (row&7 == fr&7)
  const int aBase = (wr*128 + fr) * 128;       // + m*2048
  const int bBase = 32768 + (wc*64 + fr) * 128;// + n*2048

  f32x4 acc[8][4];
  #pragma unroll
  for (int m = 0; m < 8; m++)
    #pragma unroll
    for (int n = 0; n < 4; n++)
      #pragma unroll
      for (int r = 0; r < 4; r++) acc[m][n][r] = 0.f;

  auto STAGEH = [&](int t2, int sbuf, int j0) {   // 2 wave-loads = 16 KB
    char* dst = (char*)lds + sbuf * QBUF;
    const size_t kof = (size_t)t2 * 64;
    #pragma unroll
    for (int j = j0; j < j0 + 2; j++) {
      const f16* src = (j < 4 ? A : BT) + srcOff[j] + kof;
      __builtin_amdgcn_global_load_lds((gas1)src, (las3)(dst + ldsBase + j*8192), 16, 0, 0);
    }
  };
  auto READF = [&](f16x8* av, f16x8* bv, const char* rb, int s) {
    const int ko = ((s*4 + kg) ^ x7) << 4;
    #pragma unroll
    for (int m = 0; m < 8; m++) av[m] = *(const f16x8*)(rb + aBase + m*2048 + ko);
    #pragma unroll
    for (int n = 0; n < 4; n++) bv[n] = *(const f16x8*)(rb + bBase + n*2048 + ko);
  };

  f16x8 av[8], bv[4];
  const int NT = K >> 6;
  STAGEH(0, 0, 0); STAGEH(0, 0, 2); STAGEH(0, 0, 4); STAGEH(0, 0, 6);
  asm volatile("s_waitcnt vmcnt(0)" ::: "memory");
  asm volatile("s_barrier" ::: "memory");

  for (int t = 0; t < NT; t++) {
    const char* rb = (const char*)lds + (t & 1) * QBUF;
    const int nb = (t + 1) & 1;
    const bool stg = (t + 1) < NT;

    if (stg) { STAGEH(t + 1, nb, 0); STAGEH(t + 1, nb, 2); }   // A-tile
    READF(av, bv, rb, 0);
    __builtin_amdgcn_s_setprio(1);
    #pragma unroll
    for (int m = 0; m < 8; m++)
      #pragma unroll
      for (int n = 0; n < 4; n++)
        acc[m][n] = __builtin_amdgcn_mfma_f32_16x16x32_f16(bv[n], av[m], acc[m][n], 0, 0, 0);
    __builtin_amdgcn_s_setprio(0);
    if (stg) { STAGEH(t + 1, nb, 4); STAGEH(t + 1, nb, 6); }   // B-tile
    READF(av, bv, rb, 1);
    __builtin_amdgcn_s_setprio(1);
    #pragma unroll
    for (int m = 0; m < 8; m++)
      #pragma unroll
      for (int n = 0; n < 4; n++)
        acc[m][n] = __builtin_amdgcn_mfma_f32_16x16x32_f16(bv[n], av[m], acc[m][n], 0, 0, 0);
    __builtin_amdgcn_s_setprio(0);
    if (stg) asm volatile("s_waitcnt vmcnt(0)" ::: "memory");
    asm volatile("s_barrier" ::: "memory");   // tile t+1 resident; buf[t&1] reads retired
  }

  // swapped-operand C layout: C[bm*256 + wr*128 + m*16 + fr]
  //                            [bn*256 + wc*64 + n*16 + kg*4 + r]
  const int crow = bm*256 + wr*128 + fr;    // + m*16
  const int ccol = bn*256 + wc*64 + kg*4;   // + n*16, r contiguous
  if constexpr (MODE == 2) {
    #pragma unroll
    for (int n = 0; n < 4; n++) {
      float4 bb = *(const float4*)(bias + ccol + n*16);
      #pragma unroll
      for (int m = 0; m < 8; m++) {
        float4 v;
        v.x = acc[m][n][0] + bb.x; v.y = acc[m][n][1] + bb.y;
        v.z = acc[m][n][2] + bb.z; v.w = acc[m][n][3] + bb.w;
        *(float4*)(Cf + (size_t)(crow + m*16) * N + ccol + n*16) = v;
      }
    }
  } else {
    #pragma unroll
    for (int m = 0; m < 8; m++)
      #pragma unroll
      for (int n = 0; n < 4; n++) {
        f16x4 o;
        o[0] = (f16)acc[m][n][0]; o[1] = (f16)acc[m][n][1];
        o[2] = (f16)acc[m][n][2]; o[3] = (f16)acc[m][n][3];
        *(f16x4*)(C1 + (size_t)(crow + m*16) * N + ccol + n*16) = o;
      }
  }
  if constexpr (MODE == 1) {
    // column-stat partials over this block's 256 rows.
    float s[4][4], q[4][4];
    #pragma unroll
    for (int n = 0; n < 4; n++)
      #pragma unroll
      for (int r = 0; r < 4; r++) {
        float ss = 0.f, qq = 0.f;
        #pragma unroll
        for (int m = 0; m < 8; m++) { float v = acc[m][n][r]; ss += v; qq = fmaf(v, v, qq); }
        s[n][r] = ss; q[n][r] = qq;
      }
    #pragma unroll
    for (int n = 0; n < 4; n++)
      #pragma unroll
      for (int r = 0; r < 4; r++) {
        s[n][r] += __shfl_xor(s[n][r], 1); s[n][r] += __shfl_xor(s[n][r], 2);
        s[n][r] += __shfl_xor(s[n][r], 4); s[n][r] += __shfl_xor(s[n][r], 8);
        q[n][r] += __shfl_xor(q[n][r], 1); q[n][r] += __shfl_xor(q[n][r], 2);
        q[n][r] += __shfl_xor(q[n][r], 4); q[n][r] += __shfl_xor(q[n][r], 8);
      }
    float* wred = (float*)lds;   // [sum: [wr][256]] [sq: [wr][256]] = 4 KB
    __syncthreads();
    if (fr == 0) {
      #pragma unroll
      for (int n = 0; n < 4; n++)
        #pragma unroll
        for (int r = 0; r < 4; r++) {
          int c = wc*64 + n*16 + kg*4 + r;
          wred[wr*256 + c]       = s[n][r];
          wred[512 + wr*256 + c] = q[n][r];
        }
    }
    __syncthreads();
    if (tid < 256) {
      psum[(size_t)bm * N + bn*256 + tid] = wred[tid]       + wred[256 + tid];
      psq [(size_t)bm * N + bn*256 + tid] = wred[512 + tid] + wred[768 + tid];
    }
  }
}

// ---------------- in-place mix on [M][512] (xg -> mix(xg)) ----------------
__global__ __launch_bounds__(256)
void k_mixip(f16* __restrict__ t, const float* __restrict__ Aadj) {
  __shared__ float A[441];
  int b = blockIdx.x, tid = threadIdx.x;
  for (int i = tid; i < 441; i += 256) A[i] = Aadj[i];
  __syncthreads();
  int c0 = tid * 2;
  size_t base = (size_t)b * NN * 512 + c0;
  float vx[21], vy[21];
  #pragma unroll
  for (int j = 0; j < 21; j++) {
    f16x2 v = *(const f16x2*)(t + base + (size_t)j * 512);
    vx[j] = (float)v[0]; vy[j] = (float)v[1];
  }
  #pragma unroll
  for (int i = 0; i < 21; i++) {
    float a0 = 0.f, a1 = 0.f;
    #pragma unroll
    for (int j = 0; j < 21; j++) { float w = A[i*21+j]; a0 = fmaf(w, vx[j], a0); a1 = fmaf(w, vy[j], a1); }
    f16x2 o; o[0] = (f16)a0; o[1] = (f16)a1;
    *(f16x2*)(t + base + (size_t)i * 512) = o;
  }
}

// ------- per-graph 21x21 mix, in-place + per-graph BN stats -------
__global__ __launch_bounds__(256)
void k_mix(f16* __restrict__ t, const float* __restrict__ Aadj,
           float* __restrict__ psum, float* __restrict__ psq, int C) {
  __shared__ float A[441];
  int b = blockIdx.x, tid = threadIdx.x;
  for (int i = tid; i < 441; i += 256) A[i] = Aadj[i];
  __syncthreads();
  int c0 = (blockIdx.y * 256 + tid) * 2;
  size_t base = (size_t)b * NN * C + c0;
  float vx[21], vy[21];
  #pragma unroll
  for (int j = 0; j < 21; j++) {
    f16x2 v = *(const f16x2*)(t + base + (size_t)j * C);
    vx[j] = (float)v[0]; vy[j] = (float)v[1];
  }
  float s0 = 0.f, s1 = 0.f, q0 = 0.f, q1 = 0.f;
  #pragma unroll
  for (int i = 0; i < 21; i++) {
    float a0 = 0.f, a1 = 0.f;
    #pragma unroll
    for (int j = 0; j < 21; j++) {
      float w = A[i*21 + j];
      a0 = fmaf(w, vx[j], a0);
      a1 = fmaf(w, vy[j], a1);
    }
    f16x2 o; o[0] = (f16)a0; o[1] = (f16)a1;
    *(f16x2*)(t + base + (size_t)i * C) = o;
    s0 += a0; s1 += a1;
    q0 = fmaf(a0, a0, q0); q1 = fmaf(a1, a1, q1);
  }
  float2 sv; sv.x = s0; sv.y = s1;
  float2 qv; qv.x = q0; qv.y = q1;
  *(float2*)(psum + (size_t)b * C + c0) = sv;
  *(float2*)(psq  + (size_t)b * C + c0) = qv;
}

// ---------------- reduce partials -> groups (deterministic) --------------
__global__ void k_reduce(const float* __restrict__ ps, const float* __restrict__ pq,
                         float* __restrict__ rs, float* __restrict__ rq,
                         int C, int per) {
  int c = blockIdx.x * 256 + threadIdx.x;
  int py = blockIdx.y;
  float s = 0.f, q = 0.f;
  for (int p = py*per; p < py*per + per; p++) {
    s += ps[(size_t)p*C + c];
    q += pq[(size_t)p*C + c];
  }
  rs[(size_t)py*C + c] = s;
  rq[(size_t)py*C + c] = q;
}

__global__ void k_bnparams(const float* __restrict__ psum, const float* __restrict__ psq,
                           const float* __restrict__ gamma, const float* __restrict__ beta,
                           const float* __restrict__ resbias,
                           float* __restrict__ scale, float* __restrict__ shift,
                           int C, int npart) {
  int c = blockIdx.x * 256 + threadIdx.x;
  float s = 0.f, q = 0.f;
  for (int p = 0; p < npart; p++) { s += psum[(size_t)p*C + c]; q += psq[(size_t)p*C + c]; }
  const float Minv = 1.f / (float)MROWS;
  float mean = s * Minv;
  float var = q * Minv - mean * mean;
  float sc = gamma[c] * rsqrtf(var + 1e-5f);
  float sh = beta[c] - mean * sc;
  if (resbias) sh += resbias[c];
  scale[c] = sc; shift[c] = sh;
}

// ---------------- finalize: dst = relu(g*scale + shift + res) ----------------
__global__ void k_finalize(const f16* __restrict__ g, const f16* res,
                           f16* dst, const float* __restrict__ scale,
                           const float* __restrict__ shift, int cmask) {
  size_t i8 = (size_t)blockIdx.x * 256 + threadIdx.x;
  size_t base = i8 * 8;
  int c = (int)(base & (size_t)cmask);
  f16x8 gv = *(const f16x8*)(g + base);
  f16x8 rv = *(const f16x8*)(res + base);
  f16x8 o;
  #pragma unroll
  for (int j = 0; j < 8; j++) {
    float v = (float)gv[j] * scale[c + j] + shift[c + j] + (float)rv[j];
    o[j] = (f16)fmaxf(v, 0.f);
  }
  *(f16x8*)(dst + base) = o;
}

// ---------------- fused finish + mix: hmix = mix(relu(t*sc+sh+res)) ---------
__global__ __launch_bounds__(256)
void k_finmix(const f16* t, const f16* res, f16* hout, f16* hmix,
              const float* __restrict__ scale, const float* __restrict__ shift,
              const float* __restrict__ Aadj, int C) {
  __shared__ float A[441];
  int b = blockIdx.x, tid = threadIdx.x;
  for (int i = tid; i < 441; i += 256) A[i] = Aadj[i];
  __syncthreads();
  int c0 = (blockIdx.y * 256 + tid) * 2;
  float scx = scale[c0], scy = scale[c0+1];
  float shx = shift[c0], shy = shift[c0+1];
  size_t base = (size_t)b * NN * C + c0;
  float hx[21], hy[21];
  #pragma unroll
  for (int j = 0; j < 21; j++) {
    f16x2 tv = *(const f16x2*)(t + base + (size_t)j*C);
    f16x2 rv = *(const f16x2*)(res + base + (size_t)j*C);
    hx[j] = fmaxf((float)tv[0]*scx + shx + (float)rv[0], 0.f);
    hy[j] = fmaxf((float)tv[1]*scy + shy + (float)rv[1], 0.f);
    if (hout) {
      f16x2 o; o[0] = (f16)hx[j]; o[1] = (f16)hy[j];
      *(f16x2*)(hout + base + (size_t)j*C) = o;
    }
  }
  #pragma unroll
  for (int i = 0; i < 21; i++) {
    float a0 = 0.f, a1 = 0.f;
    #pragma unroll
    for (int j = 0; j < 21; j++) { float w = A[i*21+j]; a0 = fmaf(w, hx[j], a0); a1 = fmaf(w, hy[j], a1); }
    f16x2 o; o[0] = (f16)a0; o[1] = (f16)a1;
    *(f16x2*)(hmix + base + (size_t)i*C) = o;
  }
}

// ---------------- pool (mean over 21) + BN affine -> f16 (f16x2 vec) --------
__global__ void k_pool(const f16* __restrict__ g3, const float* __restrict__ scale,
                       const float* __restrict__ shift, f16* __restrict__ pooled) {
  int b = blockIdx.x, c0 = threadIdx.x * 2;
  const f16* gb = g3 + (size_t)b * NN * 512 + c0;
  float s0 = 0.f, s1 = 0.f;
  #pragma unroll
  for (int n = 0; n < NN; n++) {
    f16x2 v = *(const f16x2*)(gb + (size_t)n * 512);
    s0 += (float)v[0]; s1 += (float)v[1];
  }
  f16x2 o;
  o[0] = (f16)((s0 * (1.f/21.f)) * scale[c0]   + shift[c0]);
  o[1] = (f16)((s1 * (1.f/21.f)) * scale[c0+1] + shift[c0+1]);
  *(f16x2*)(pooled + (size_t)b * 512 + c0) = o;
}

extern "C" void kernel_launch(void* const* d_in, const int* in_sizes, int n_in,
                              void* d_out, int out_size, void* d_ws, size_t ws_size,
                              hipStream_t stream) {
  const float* x     = (const float*)d_in[0];
  const float* nv1   = (const float*)d_in[2];
  const float* nv2   = (const float*)d_in[3];
  const float* se_w1 = (const float*)d_in[4];
  const float* se_w2 = (const float*)d_in[5];
  const float* W1    = (const float*)d_in[6];
  const float* W2    = (const float*)d_in[8];
  const float* W3    = (const float*)d_in[10];
  const float* bn1g  = (const float*)d_in[12];
  const float* bn1b  = (const float*)d_in[13];
  const float* bn2g  = (const float*)d_in[14];
  const float* bn2b  = (const float*)d_in[15];
  const float* bn3g  = (const float*)d_in[16];
  const float* bn3b  = (const float*)d_in[17];
  const float* rs1w  = (const float*)d_in[18];
  const float* rs1b  = (const float*)d_in[19];
  const float* fcw   = (const float*)d_in[20];
  const float* fcb   = (const float*)d_in[21];
  float* out = (float*)d_out;

  char* ws = (char*)d_ws;
  size_t off = 0;
  auto alloc = [&](size_t bytes) -> char* {
    char* p = ws + off;
    off = (off + bytes + 255) & ~(size_t)255;
    return p;
  };

  // total ws footprint ~470 MB (known-good <=484; 738 aborted in round 7)
  float* A_adj = (float*)alloc(441 * 4);
  f16* W1T  = (f16*)alloc((size_t)1024 * 512 * 2);
  f16* RS1T = (f16*)alloc((size_t)1024 * 512 * 2);
  f16* W2T  = (f16*)alloc((size_t)1024 * 1024 * 2);
  f16* W3T  = (f16*)alloc((size_t)512 * 1024 * 2);
  f16* FCWT = (f16*)alloc((size_t)1024 * 512 * 2);
  float* psum = (float*)alloc((size_t)NB * 1024 * 4);    // 16MB; aliases xm
  float* psq  = (float*)alloc((size_t)NB * 1024 * 4);    // 16MB; aliases yv
  float* y1   = (float*)alloc((size_t)NB * 128 * 4);
  float* rsum = (float*)alloc((size_t)32 * 1024 * 4);
  float* rsq  = (float*)alloc((size_t)32 * 1024 * 4);
  float* sc1 = (float*)alloc(1024 * 4);
  float* sh1 = (float*)alloc(1024 * 4);
  float* sc2 = (float*)alloc(1024 * 4);
  float* sh2 = (float*)alloc(1024 * 4);
  float* sc3 = (float*)alloc(1024 * 4);
  float* sh3 = (float*)alloc(1024 * 4);
  f16* pooled = (f16*)alloc((size_t)NB * 512 * 2);
  f16* G = (f16*)alloc((size_t)MROWS * 512 * 2);     // xg -> xgm -> T3
  f16* R = (f16*)alloc((size_t)MROWS * 1024 * 2);    // R1 -> h1
  f16* T = (f16*)alloc((size_t)MROWS * 1024 * 2);    // T1 -> T2/t2m -> h2m
  float* xm = psum;   // dead before psum first written
  float* yv = psq;    // dead after k_gate, before psq first written
  (void)ws_size; (void)in_sizes; (void)n_in; (void)out_size;

  // adjacency + batched weight transposes (1 launch)
  k_adj<<<1, 512, 0, stream>>>(nv1, nv2, A_adj);
  k_transpose_all<<<3072, dim3(32, 8), 0, stream>>>(W1, rs1w, W2, W3, fcw,
                                                    W1T, RS1T, W2T, W3T, FCWT);

  // SE path + gate
  k_mean<<<NB, 256, 0, stream>>>(x, xm);
  k_se1<<<NB, 128, 0, stream>>>(xm, se_w1, y1);
  k_se2<<<NB, 512, 0, stream>>>(y1, se_w2, yv);
  k_gate<<<21504, 256, 0, stream>>>(x, yv, G);

  // layer 1: R1 = xg@rs1w; xgm = mix(xg) in place; T1 = xgm@W1 (+fused stats)
  // M-tiles = 86016/256 = 336; N=1024 -> 4 N-tiles (lgn=2) -> 1344 blocks
  k_gemm256<0><<<1344, 512, 0, stream>>>(G, RS1T, R, nullptr, nullptr, nullptr, nullptr, 1024, 512, 2);
  k_mixip<<<NB, 256, 0, stream>>>(G, A_adj);
  k_gemm256<1><<<1344, 512, 0, stream>>>(G, W1T, T, nullptr, nullptr, psum, psq, 1024, 512, 2);
  k_reduce<<<dim3(4, 24), 256, 0, stream>>>(psum, psq, rsum, rsq, 1024, 14);   // 24*14 = 336
  k_bnparams<<<4, 256, 0, stream>>>(rsum, rsq, bn1g, bn1b, rs1b, sc1, sh1, 1024, 24);
  k_finalize<<<43008, 256, 0, stream>>>(T, R, R, sc1, sh1, 1023);     // h1 -> R

  // layer 2: T2 = h1@W2; mix+stats in place; h2m = mix(relu(BN(t2m)+h1)) -> T
  k_gemm256<0><<<1344, 512, 0, stream>>>(R, W2T, T, nullptr, nullptr, nullptr, nullptr, 1024, 1024, 2);
  k_mix<<<dim3(NB, 2), 256, 0, stream>>>(T, A_adj, psum, psq, 1024);
  k_reduce<<<dim3(4, 32), 256, 0, stream>>>(psum, psq, rsum, rsq, 1024, 128);
  k_bnparams<<<4, 256, 0, stream>>>(rsum, rsq, bn2g, bn2b, nullptr, sc2, sh2, 1024, 32);
  k_finmix<<<dim3(NB, 2), 256, 0, stream>>>(T, R, nullptr, T, sc2, sh2, A_adj, 1024);

  // layer 3: T3 = h2m@W3 (+fused stats) -> G ; N=512 -> 2 N-tiles (lgn=1)
  k_gemm256<1><<<672, 512, 0, stream>>>(T, W3T, G, nullptr, nullptr, psum, psq, 512, 1024, 1);
  k_reduce<<<dim3(2, 24), 256, 0, stream>>>(psum, psq, rsum, rsq, 512, 14);
  k_bnparams<<<2, 256, 0, stream>>>(rsum, rsq, bn3g, bn3b, nullptr, sc3, sh3, 512, 24);

  // pool + fc : M=4096 -> 16 m-tiles x 4 n-tiles = 64 blocks
  k_pool<<<NB, 256, 0, stream>>>(G, sc3, sh3, pooled);
  k_gemm256<2><<<64, 512, 0, stream>>>(pooled, FCWT, nullptr, fcb, out, nullptr, nullptr, 1024, 512, 2);
}